// Round 8
// baseline (288.904 us; speedup 1.0000x reference)
//
#include <hip/hip_runtime.h>
#include <stdint.h>
#include <stddef.h>

#define NN 50000
#define NP 50048            // padded rows (782 * 64)
#define NE 800000
#define NG 128

#define NBKT 256            // dst buckets
#define NPB 196             // nodes per bucket (196*256 = 50176 >= NN)
#define BCAP 4096           // bucket capacity (mean ~3125 + 17 sigma)
#define TILE_E 1536         // edges per partition workgroup
#define PARTB 521           // ceil(NE / TILE_E)
#define AGB 3125            // agg_pool blocks per chunk (3125 * 16 nodes = 50000)
#define TFB 782             // transform/aggtf blocks (NP/64)

typedef __attribute__((ext_vector_type(8))) short bf16x8;
typedef __attribute__((ext_vector_type(4))) float f32x4;
typedef __attribute__((ext_vector_type(4))) unsigned int u32x4;
typedef unsigned short ushort_t;
typedef unsigned int uint_t;

// float -> bf16 (RNE) and bf16x2 unpack helpers
static __device__ inline ushort_t f2b(float f) {
    union { float f; uint_t u; } v; v.f = f;
    uint_t r = v.u + 0x7FFFu + ((v.u >> 16) & 1u);
    return (ushort_t)(r >> 16);
}
static __device__ inline float blo(uint_t u) {
    union { uint_t u; float f; } v; v.u = u << 16; return v.f;
}
static __device__ inline float bhi(uint_t u) {
    union { uint_t u; float f; } v; v.u = u & 0xFFFF0000u; return v.f;
}

// ---------------- K1: partition (blocks 0..PARTB-1) + zero out + inv_cnt (rest) --------
__launch_bounds__(256) static __global__
void part_zero_kernel(const int* __restrict__ src, const int* __restrict__ dst,
                      int* __restrict__ bucket_cnt, uint_t* __restrict__ part,
                      float* __restrict__ out, const int* __restrict__ batch,
                      float* __restrict__ inv_cnt) {
    __shared__ int hist[NBKT];
    int tid = threadIdx.x;
    if (blockIdx.x < PARTB) {
        hist[tid] = 0;
        __syncthreads();
        int base = blockIdx.x * TILE_E;
        int end = min(base + TILE_E, NE);
        for (int i = base + tid; i < end; i += 256)
            atomicAdd(&hist[dst[i] / NPB], 1);
        __syncthreads();
        int r = atomicAdd(&bucket_cnt[tid], hist[tid]);   // reserve
        __syncthreads();
        hist[tid] = r;                                    // reuse as cursor
        __syncthreads();
        for (int i = base + tid; i < end; i += 256) {
            int s = src[i], d = dst[i];
            int b = d / NPB;
            int dl = d - b * NPB;
            int p = atomicAdd(&hist[b], 1);
            part[b * BCAP + p] = ((uint_t)dl << 16) | (uint_t)s;
        }
    } else {
        int gid = (blockIdx.x - PARTB) * 256 + tid;
        if (gid < NG * 64) out[gid] = 0.f;                // d_out is 0xAA-poisoned
        if (gid < NG) {
            int g = gid;
            int lo = 0, hi = NN;
            while (lo < hi) { int m = (lo + hi) >> 1; if (batch[m] < g) lo = m + 1; else hi = m; }
            int start = lo;
            hi = NN;
            while (lo < hi) { int m = (lo + hi) >> 1; if (batch[m] < g + 1) lo = m + 1; else hi = m; }
            inv_cnt[g] = 1.f / (float)max(lo - start, 1);
        }
    }
}

// ---------------- csr_build body (per-bucket CSR, u16 indices + packed offs|deg) -------
static __device__ void csr_build_body(int b, char* smem, const uint_t* __restrict__ part,
                                      const int* __restrict__ bucket_cnt,
                                      uint_t* __restrict__ od, ushort_t* __restrict__ csr) {
    uint_t* stage = (uint_t*)smem;                       // 16384 B
    ushort_t* cstage = (ushort_t*)(smem + 16384);        // 8192 B
    int* cnt_s = (int*)(smem + 24576);                   // 1024 B
    int* scan_l = (int*)(smem + 25600);                  // 1024 B
    int* cur_l = (int*)(smem + 26624);                   // 1024 B
    int tid = threadIdx.x;
    int bc = bucket_cnt[tid];
    cnt_s[tid] = bc;
    scan_l[tid] = bc;
    __syncthreads();
    for (int off = 1; off < NBKT; off <<= 1) {
        int t = (tid >= off) ? scan_l[tid - off] : 0;
        __syncthreads();
        scan_l[tid] += t;
        __syncthreads();
    }
    int base = scan_l[b] - cnt_s[b];
    int n = cnt_s[b];
    __syncthreads();
    cnt_s[tid] = 0;                           // reuse as deg_l
    __syncthreads();
    for (int i = tid; i < n; i += 256) {
        uint_t e = part[(size_t)b * BCAP + i];
        stage[i] = e;
        atomicAdd(&cnt_s[e >> 16], 1);
    }
    __syncthreads();
    int v = cnt_s[tid];
    scan_l[tid] = v;
    __syncthreads();
    for (int off = 1; off < NBKT; off <<= 1) {
        int t = (tid >= off) ? scan_l[tid - off] : 0;
        __syncthreads();
        scan_l[tid] += t;
        __syncthreads();
    }
    int ex = scan_l[tid] - v;
    scan_l[tid] = ex;
    cur_l[tid] = 0;
    __syncthreads();
    int g = b * NPB + tid;
    // packed descriptor: offs in bits [31:8], deg in bits [7:0]
    if (tid < NPB && g < NN) od[g] = ((uint_t)(base + ex) << 8) | (uint_t)v;
    for (int i = tid; i < n; i += 256) {
        uint_t e = stage[i];
        int dl = e >> 16;
        int p = atomicAdd(&cur_l[dl], 1);
        cstage[scan_l[dl] + p] = (ushort_t)(e & 0xFFFFu);
    }
    __syncthreads();
    for (int i = tid; i < n; i += 256) csr[base + i] = cstage[i];
}

// ---------------- weight staging + MFMA + C-write (shared epilogue) ----------------
template <int DOUT, int NT>
static __device__ void mfma_store(int bid, char* smem, bf16x8 a0, bf16x8 a1, bf16x8 a2,
                                  const float* __restrict__ Wl, const float* __restrict__ bias,
                                  const float* __restrict__ Wr,
                                  ushort_t* __restrict__ tlc, ushort_t* __restrict__ trc) {
    constexpr int DIN = 96;
    short* w_s = (short*)smem;                // NT*3*64*8 shorts
    int tid = threadIdx.x;
    for (int idx = tid; idx < NT * 3 * 64; idx += 256) {
        int ci = idx >> 6, ln = idx & 63;
        int t = ci / 3, s = ci - 3 * t;
        int o = t * 16 + (ln & 15);
        int c0 = s * 32 + (ln >> 4) * 8;
        const float* wrow = (o < DOUT) ? (Wl + (size_t)o * DIN)
                                       : (Wr + (size_t)(o - DOUT) * DIN);
        float4 v0 = *(const float4*)(wrow + c0);
        float4 v1 = *(const float4*)(wrow + c0 + 4);
        bf16x8 pk;
        pk[0] = (short)f2b(v0.x); pk[1] = (short)f2b(v0.y);
        pk[2] = (short)f2b(v0.z); pk[3] = (short)f2b(v0.w);
        pk[4] = (short)f2b(v1.x); pk[5] = (short)f2b(v1.y);
        pk[6] = (short)f2b(v1.z); pk[7] = (short)f2b(v1.w);
        *(bf16x8*)&w_s[idx * 8] = pk;
    }
    __syncthreads();
    int lane = tid & 63;
    int m0 = bid * 64 + (tid >> 6) * 16;
    const bf16x8* wp = (const bf16x8*)w_s + lane;
    f32x4 acc[NT];
#pragma unroll
    for (int t = 0; t < NT; t++) {
        acc[t] = (f32x4){0.f, 0.f, 0.f, 0.f};
        acc[t] = __builtin_amdgcn_mfma_f32_16x16x32_bf16(a0, wp[(t * 3 + 0) * 64], acc[t], 0, 0, 0);
        acc[t] = __builtin_amdgcn_mfma_f32_16x16x32_bf16(a1, wp[(t * 3 + 1) * 64], acc[t], 0, 0, 0);
        acc[t] = __builtin_amdgcn_mfma_f32_16x16x32_bf16(a2, wp[(t * 3 + 2) * 64], acc[t], 0, 0, 0);
    }
    int quad = lane >> 4, col = lane & 15;
#pragma unroll
    for (int t = 0; t < NT; t++) {
        int o = t * 16 + col;
        bool is_r = (o >= DOUT);
        float bv = is_r ? bias[o - DOUT] : 0.f;
        ushort_t* outp = is_r ? trc : tlc;
        int oo = is_r ? (o - DOUT) : o;
        int cch = oo >> 5, f = oo & 31;
        ushort_t* ob = outp + ((size_t)cch * NN) * 32 + f;
#pragma unroll
        for (int r = 0; r < 4; r++) {
            int node = m0 + quad * 4 + r;
            if (node < NN) ob[(size_t)node * 32] = f2b(acc[t][r] + bv);
        }
    }
}

// ---------------- K2: csr_build (blocks 0..255) + transform layer0 (rest) ----------------
__launch_bounds__(256) static __global__
void csr_tf0_kernel(const uint_t* __restrict__ part, const int* __restrict__ bucket_cnt,
                    uint_t* __restrict__ od, ushort_t* __restrict__ csr,
                    const float* __restrict__ x, const float* __restrict__ Wl0,
                    const float* __restrict__ b0, const float* __restrict__ Wr0,
                    ushort_t* __restrict__ tlc, ushort_t* __restrict__ trc) {
    __shared__ __align__(16) char smem[36864];
    if (blockIdx.x < NBKT) {
        csr_build_body(blockIdx.x, smem, part, bucket_cnt, od, csr);
    } else {
        // layer 0: read x (fp32) directly, convert to A-frags in-register
        int bid = blockIdx.x - NBKT;
        int tid = threadIdx.x;
        int lane = tid & 63;
        int row = bid * 64 + (tid >> 6) * 16 + (lane & 15);
        const float* xr = x + (size_t)min(row, NN - 1) * 96 + (lane >> 4) * 8;
        bf16x8 a0, a1, a2;
#pragma unroll
        for (int s = 0; s < 3; s++) {
            float4 v0 = *(const float4*)(xr + s * 32);
            float4 v1 = *(const float4*)(xr + s * 32 + 4);
            bf16x8 pk;
            pk[0] = (short)f2b(v0.x); pk[1] = (short)f2b(v0.y);
            pk[2] = (short)f2b(v0.z); pk[3] = (short)f2b(v0.w);
            pk[4] = (short)f2b(v1.x); pk[5] = (short)f2b(v1.y);
            pk[6] = (short)f2b(v1.z); pk[7] = (short)f2b(v1.w);
            if (s == 0) a0 = pk; else if (s == 1) a1 = pk; else a2 = pk;
        }
        mfma_store<96, 12>(bid, smem, a0, a1, a2, Wl0, b0, Wr0, tlc, trc);
    }
}

// ---------------- gather inner loop (R3-verified tier cascade) ----------------
static __device__ inline void gather_accum(const uint_t* __restrict__ tl,
                                           const ushort_t* __restrict__ csr,
                                           int off, int dg, int ng, int fl,
                                           float* __restrict__ acc) {
    int k = 0;
    for (; k + 16 <= dg; k += 16) {
        int s0 = csr[off + k + ng];
        int s1 = csr[off + k + 4 + ng];
        int s2 = csr[off + k + 8 + ng];
        int s3 = csr[off + k + 12 + ng];
        uint4 a0 = *(const uint4*)(tl + (size_t)s0 * 16 + 4 * fl);
        uint4 a1 = *(const uint4*)(tl + (size_t)s1 * 16 + 4 * fl);
        uint4 a2 = *(const uint4*)(tl + (size_t)s2 * 16 + 4 * fl);
        uint4 a3 = *(const uint4*)(tl + (size_t)s3 * 16 + 4 * fl);
        acc[0] += (blo(a0.x) + blo(a1.x)) + (blo(a2.x) + blo(a3.x));
        acc[1] += (bhi(a0.x) + bhi(a1.x)) + (bhi(a2.x) + bhi(a3.x));
        acc[2] += (blo(a0.y) + blo(a1.y)) + (blo(a2.y) + blo(a3.y));
        acc[3] += (bhi(a0.y) + bhi(a1.y)) + (bhi(a2.y) + bhi(a3.y));
        acc[4] += (blo(a0.z) + blo(a1.z)) + (blo(a2.z) + blo(a3.z));
        acc[5] += (bhi(a0.z) + bhi(a1.z)) + (bhi(a2.z) + bhi(a3.z));
        acc[6] += (blo(a0.w) + blo(a1.w)) + (blo(a2.w) + blo(a3.w));
        acc[7] += (bhi(a0.w) + bhi(a1.w)) + (bhi(a2.w) + bhi(a3.w));
    }
    if (k + 8 <= dg) {
        int s0 = csr[off + k + ng];
        int s1 = csr[off + k + 4 + ng];
        uint4 a0 = *(const uint4*)(tl + (size_t)s0 * 16 + 4 * fl);
        uint4 a1 = *(const uint4*)(tl + (size_t)s1 * 16 + 4 * fl);
        acc[0] += blo(a0.x) + blo(a1.x); acc[1] += bhi(a0.x) + bhi(a1.x);
        acc[2] += blo(a0.y) + blo(a1.y); acc[3] += bhi(a0.y) + bhi(a1.y);
        acc[4] += blo(a0.z) + blo(a1.z); acc[5] += bhi(a0.z) + bhi(a1.z);
        acc[6] += blo(a0.w) + blo(a1.w); acc[7] += bhi(a0.w) + bhi(a1.w);
        k += 8;
    }
    if (k + 4 <= dg) {
        int s0 = csr[off + k + ng];
        uint4 a0 = *(const uint4*)(tl + (size_t)s0 * 16 + 4 * fl);
        acc[0] += blo(a0.x); acc[1] += bhi(a0.x);
        acc[2] += blo(a0.y); acc[3] += bhi(a0.y);
        acc[4] += blo(a0.z); acc[5] += bhi(a0.z);
        acc[6] += blo(a0.w); acc[7] += bhi(a0.w);
        k += 4;
    }
    if (ng < dg - k) {
        int s0 = csr[off + k + ng];
        uint4 a0 = *(const uint4*)(tl + (size_t)s0 * 16 + 4 * fl);
        acc[0] += blo(a0.x); acc[1] += bhi(a0.x);
        acc[2] += blo(a0.y); acc[3] += bhi(a0.y);
        acc[4] += blo(a0.z); acc[5] += bhi(a0.z);
        acc[6] += blo(a0.w); acc[7] += bhi(a0.w);
    }
}

// ---------------- fused agg + transform (R8) ----------------
// One block = 64 nodes. Gathers chunk-by-chunk (3.2 MB L2-resident working set
// preserved - R4 lesson), stages [64][96] bf16 h-tile in LDS, then MFMA transform
// in the same block (the h-row dependency is block-local). Kills h1b/h2b round trips
// and 2 dispatches. Ping-pong tlc/trc buffers avoid cross-block RW hazard.
template <int DOUT, int NT>
__launch_bounds__(256, 4) static __global__
void aggtf_kernel(const ushort_t* __restrict__ tlin, const ushort_t* __restrict__ trin,
                  const uint_t* __restrict__ od, const ushort_t* __restrict__ csr,
                  const float* __restrict__ Wl, const float* __restrict__ bias,
                  const float* __restrict__ Wr,
                  ushort_t* __restrict__ tlo, ushort_t* __restrict__ tro) {
    constexpr int SMEM = (NT * 3 * 64 * 16 > 12288) ? NT * 3 * 64 * 16 : 12288;
    __shared__ __align__(16) char smem[SMEM];           // hbuf overlaps w_s (sequential use)
    uint_t* hbuf = (uint_t*)smem;                        // [64][48] uints = 12288 B
    int tid = threadIdx.x;
    int bid = blockIdx.x;
    int lane16 = tid & 15;
    int ng = lane16 >> 2, fl = lane16 & 3;
    // ---- phase 1: gather-agg 64 nodes, chunk-major (4 groups of 16 nodes per chunk)
    for (int c = 0; c < 3; c++) {
        const uint_t* tl = (const uint_t*)tlin + (size_t)c * NN * 16;
        const uint_t* trb = (const uint_t*)trin + (size_t)c * NN * 16;
#pragma unroll
        for (int g = 0; g < 4; g++) {
            int nloc = g * 16 + (tid >> 4);
            int node = bid * 64 + nloc;
            uint_t pd = od[min(node, NN - 1)];
            int off = (int)(pd >> 8);
            int dg = (node < NN) ? (int)(pd & 255u) : 0;
            float acc[8];
#pragma unroll
            for (int q = 0; q < 8; q++) acc[q] = 0.f;
            gather_accum(tl, csr, off, dg, ng, fl, acc);
#pragma unroll
            for (int q = 0; q < 8; q++) {
                acc[q] += __shfl_xor(acc[q], 4, 64);
                acc[q] += __shfl_xor(acc[q], 8, 64);
            }
            float s = 1.f / (float)max(dg, 1);
            u32x4 t = __builtin_nontemporal_load(
                (const u32x4*)(trb + (size_t)min(node, NN - 1) * 16 + 4 * fl));
            if (ng == 0) {
                float v0 = fmaxf(fmaf(acc[0], s, blo(t.x)), 0.f);
                float v1 = fmaxf(fmaf(acc[1], s, bhi(t.x)), 0.f);
                float v2 = fmaxf(fmaf(acc[2], s, blo(t.y)), 0.f);
                float v3 = fmaxf(fmaf(acc[3], s, bhi(t.y)), 0.f);
                float v4 = fmaxf(fmaf(acc[4], s, blo(t.z)), 0.f);
                float v5 = fmaxf(fmaf(acc[5], s, bhi(t.z)), 0.f);
                float v6 = fmaxf(fmaf(acc[6], s, blo(t.w)), 0.f);
                float v7 = fmaxf(fmaf(acc[7], s, bhi(t.w)), 0.f);
                u32x4 o;
                o.x = (uint_t)f2b(v0) | ((uint_t)f2b(v1) << 16);
                o.y = (uint_t)f2b(v2) | ((uint_t)f2b(v3) << 16);
                o.z = (uint_t)f2b(v4) | ((uint_t)f2b(v5) << 16);
                o.w = (uint_t)f2b(v6) | ((uint_t)f2b(v7) << 16);
                *(u32x4*)&hbuf[nloc * 48 + c * 16 + 4 * fl] = o;
            }
        }
    }
    __syncthreads();
    // ---- phase 2: A-frags from LDS h-tile into registers
    int lane = tid & 63;
    int row = (tid >> 6) * 16 + (lane & 15);
    const ushort_t* hb = (const ushort_t*)smem;
    const ushort_t* hr = hb + row * 96 + (lane >> 4) * 8;
    bf16x8 a0 = *(const bf16x8*)(hr);
    bf16x8 a1 = *(const bf16x8*)(hr + 32);
    bf16x8 a2 = *(const bf16x8*)(hr + 64);
    __syncthreads();    // hbuf dead; w_s may overwrite
    // ---- phase 3: stage weights, MFMA, C-write (chunk-major out)
    mfma_store<DOUT, NT>(bid, smem, a0, a1, a2, Wl, bias, Wr, tlo, tro);
}

// ---------------- final agg + pool fused (D=64, no relu), pre-divided atomics -------
__launch_bounds__(256) static __global__
void agg_pool_kernel(const ushort_t* __restrict__ tlc, const ushort_t* __restrict__ trc,
                     const uint_t* __restrict__ od, const ushort_t* __restrict__ csr,
                     const int* __restrict__ batch,
                     const float* __restrict__ inv_cnt, float* __restrict__ out) {
    __shared__ float hsum[16][32];
    __shared__ int gids[16];
    int bx = blockIdx.x;
    int c = bx / AGB;
    int b = bx - c * AGB;
    int tid = threadIdx.x;
    int nl = tid >> 4;
    int node = b * 16 + nl;
    int lane = tid & 15;
    int ng = lane >> 2, fl = lane & 3;
    if (tid < 16) gids[tid] = batch[b * 16 + tid];
    const uint_t* tl = (const uint_t*)tlc + (size_t)c * NN * 16;
    uint_t pd = od[node];
    int off = (int)(pd >> 8), dg = (int)(pd & 255u);
    float acc[8];
#pragma unroll
    for (int q = 0; q < 8; q++) acc[q] = 0.f;
    gather_accum(tl, csr, off, dg, ng, fl, acc);
#pragma unroll
    for (int q = 0; q < 8; q++) {
        acc[q] += __shfl_xor(acc[q], 4, 64);
        acc[q] += __shfl_xor(acc[q], 8, 64);
    }
    float s = 1.f / (float)max(dg, 1);
    u32x4 t = __builtin_nontemporal_load(
        (const u32x4*)((const uint_t*)trc + (size_t)c * NN * 16 + (size_t)node * 16 + 4 * fl));
    if (ng == 0) {
        hsum[nl][8 * fl + 0] = fmaf(acc[0], s, blo(t.x));
        hsum[nl][8 * fl + 1] = fmaf(acc[1], s, bhi(t.x));
        hsum[nl][8 * fl + 2] = fmaf(acc[2], s, blo(t.y));
        hsum[nl][8 * fl + 3] = fmaf(acc[3], s, bhi(t.y));
        hsum[nl][8 * fl + 4] = fmaf(acc[4], s, blo(t.z));
        hsum[nl][8 * fl + 5] = fmaf(acc[5], s, bhi(t.z));
        hsum[nl][8 * fl + 6] = fmaf(acc[6], s, blo(t.w));
        hsum[nl][8 * fl + 7] = fmaf(acc[7], s, bhi(t.w));
    }
    __syncthreads();
    if (tid < 32) {
        int gcur = gids[0];
        float ps = 0.f;
        for (int j = 0; j < 16; j++) {
            int g = gids[j];
            if (g != gcur) {
                atomicAdd(&out[gcur * 64 + c * 32 + tid], ps * inv_cnt[gcur]);
                ps = 0.f; gcur = g;
            }
            ps += hsum[j][tid];
        }
        atomicAdd(&out[gcur * 64 + c * 32 + tid], ps * inv_cnt[gcur]);
    }
}

// ---------------- launch: 5 dispatches (was 7) ----------------
extern "C" void kernel_launch(void* const* d_in, const int* in_sizes, int n_in,
                              void* d_out, int out_size, void* d_ws, size_t ws_size,
                              hipStream_t stream) {
    (void)in_sizes; (void)n_in; (void)out_size; (void)ws_size;
    const float* x   = (const float*)d_in[0];
    const int*   ei  = (const int*)d_in[1];
    const int*   bat = (const int*)d_in[2];
    const float* Wl0 = (const float*)d_in[3];
    const float* b0  = (const float*)d_in[4];
    const float* Wr0 = (const float*)d_in[5];
    const float* Wl1 = (const float*)d_in[6];
    const float* b1  = (const float*)d_in[7];
    const float* Wr1 = (const float*)d_in[8];
    const float* Wl2 = (const float*)d_in[9];
    const float* b2  = (const float*)d_in[10];
    const float* Wr2 = (const float*)d_in[11];
    float* out = (float*)d_out;
    const int* src = ei;
    const int* dst = ei + NE;

    char* p = (char*)d_ws;
    auto carve = [&](size_t bytes) -> char* {
        char* r = p;
        p += (bytes + 255) & ~(size_t)255;
        return r;
    };
    uint_t*   od     = (uint_t*)carve((size_t)NN * 4);          // packed offs<<8 | deg
    int*      bucket_cnt = (int*)carve(NBKT * 4);
    float*    inv_cnt = (float*)carve(NG * 4);
    uint_t*   part   = (uint_t*)carve((size_t)NBKT * BCAP * 4);
    ushort_t* csr    = (ushort_t*)carve((size_t)NE * 2);        // u16 src indices
    ushort_t* tlcA   = (ushort_t*)carve((size_t)3 * NN * 32 * 2);  // chunk-major ping
    ushort_t* trcA   = (ushort_t*)carve((size_t)3 * NN * 32 * 2);
    ushort_t* tlcB   = (ushort_t*)carve((size_t)3 * NN * 32 * 2);  // chunk-major pong
    ushort_t* trcB   = (ushort_t*)carve((size_t)3 * NN * 32 * 2);

    dim3 b256(256);
    hipMemsetAsync(bucket_cnt, 0, NBKT * 4, stream);

    part_zero_kernel<<<dim3(PARTB + 32), b256, 0, stream>>>(src, dst, bucket_cnt, part,
                                                            out, bat, inv_cnt);
    csr_tf0_kernel<<<dim3(NBKT + TFB), b256, 0, stream>>>(part, bucket_cnt, od, csr,
                                                          x, Wl0, b0, Wr0, tlcA, trcA);
    aggtf_kernel<96, 12><<<dim3(TFB), b256, 0, stream>>>(tlcA, trcA, od, csr,
                                                         Wl1, b1, Wr1, tlcB, trcB);
    aggtf_kernel<64, 8><<<dim3(TFB), b256, 0, stream>>>(tlcB, trcB, od, csr,
                                                        Wl2, b2, Wr2, tlcA, trcA);
    agg_pool_kernel<<<dim3(2 * AGB), b256, 0, stream>>>(tlcA, trcA, od, csr, bat,
                                                        inv_cnt, out);
}

// Round 9
// 242.511 us; speedup vs baseline: 1.1913x; 1.1913x over previous
//
#include <hip/hip_runtime.h>
#include <stdint.h>
#include <stddef.h>

#define NN 50000
#define NE 800000
#define NG 128

#define NBKT 256            // dst buckets
#define NPB 196             // nodes per bucket (196*256 = 50176 >= NN)
#define BCAP 4096           // bucket capacity (mean ~3125 + 17 sigma)
#define TILE_E 1536         // edges per partition workgroup
#define PARTB 521           // ceil(NE / TILE_E)
#define AGB 3125            // agg_pool blocks per chunk (3125 * 16 nodes = 50000)
#define AGB32 1563          // aggtf blocks (1563 * 32 nodes = 50016 >= NN)
#define TFB 782             // layer-0 transform blocks (50048/64)

// wpack frag counts: NT*3*64
#define NF0 2304            // layer0: NT=12
#define NF1 2304            // layer1: NT=12
#define NF2 1536            // layer2: NT=8

typedef __attribute__((ext_vector_type(8))) short bf16x8;
typedef __attribute__((ext_vector_type(4))) float f32x4;
typedef __attribute__((ext_vector_type(4))) unsigned int u32x4;
typedef unsigned short ushort_t;
typedef unsigned int uint_t;

// float -> bf16 (RNE) and bf16x2 unpack helpers
static __device__ inline ushort_t f2b(float f) {
    union { float f; uint_t u; } v; v.f = f;
    uint_t r = v.u + 0x7FFFu + ((v.u >> 16) & 1u);
    return (ushort_t)(r >> 16);
}
static __device__ inline float blo(uint_t u) {
    union { uint_t u; float f; } v; v.u = u << 16; return v.f;
}
static __device__ inline float bhi(uint_t u) {
    union { uint_t u; float f; } v; v.u = u & 0xFFFF0000u; return v.f;
}

// pack one weight fragment (same layout as the old LDS w_s staging)
static __device__ inline void pack_frag(int idx, int DOUT,
                                        const float* __restrict__ Wl,
                                        const float* __restrict__ Wr,
                                        ushort_t* __restrict__ wpack) {
    int ci = idx >> 6, ln = idx & 63;
    int t = ci / 3, s = ci - 3 * t;
    int o = t * 16 + (ln & 15);
    int c0 = s * 32 + (ln >> 4) * 8;
    const float* wrow = (o < DOUT) ? (Wl + (size_t)o * 96)
                                   : (Wr + (size_t)(o - DOUT) * 96);
    float4 v0 = *(const float4*)(wrow + c0);
    float4 v1 = *(const float4*)(wrow + c0 + 4);
    bf16x8 pk;
    pk[0] = (short)f2b(v0.x); pk[1] = (short)f2b(v0.y);
    pk[2] = (short)f2b(v0.z); pk[3] = (short)f2b(v0.w);
    pk[4] = (short)f2b(v1.x); pk[5] = (short)f2b(v1.y);
    pk[6] = (short)f2b(v1.z); pk[7] = (short)f2b(v1.w);
    *(bf16x8*)&wpack[(size_t)idx * 8] = pk;
}

// ---------------- K1: partition + zero out + inv_cnt + weight pre-pack ----------------
__launch_bounds__(256) static __global__
void part_zero_kernel(const int* __restrict__ src, const int* __restrict__ dst,
                      int* __restrict__ bucket_cnt, uint_t* __restrict__ part,
                      float* __restrict__ out, const int* __restrict__ batch,
                      float* __restrict__ inv_cnt,
                      const float* __restrict__ Wl0, const float* __restrict__ Wr0,
                      const float* __restrict__ Wl1, const float* __restrict__ Wr1,
                      const float* __restrict__ Wl2, const float* __restrict__ Wr2,
                      ushort_t* __restrict__ wp0, ushort_t* __restrict__ wp1,
                      ushort_t* __restrict__ wp2) {
    __shared__ int hist[NBKT];
    int tid = threadIdx.x;
    if (blockIdx.x < PARTB) {
        hist[tid] = 0;
        __syncthreads();
        int base = blockIdx.x * TILE_E;
        int end = min(base + TILE_E, NE);
        for (int i = base + tid; i < end; i += 256)
            atomicAdd(&hist[dst[i] / NPB], 1);
        __syncthreads();
        int r = atomicAdd(&bucket_cnt[tid], hist[tid]);   // reserve
        __syncthreads();
        hist[tid] = r;                                    // reuse as cursor
        __syncthreads();
        for (int i = base + tid; i < end; i += 256) {
            int s = src[i], d = dst[i];
            int b = d / NPB;
            int dl = d - b * NPB;
            int p = atomicAdd(&hist[b], 1);
            part[b * BCAP + p] = ((uint_t)dl << 16) | (uint_t)s;
        }
    } else {
        int gid = (blockIdx.x - PARTB) * 256 + tid;
        if (gid < NG * 64) out[gid] = 0.f;                // d_out is 0xAA-poisoned
        // weight pre-pack: fp32 W -> bf16 MFMA B-frags in global (L2-hot, shared by all)
        if (gid < NF0) pack_frag(gid, 96, Wl0, Wr0, wp0);
        else if (gid < NF0 + NF1) pack_frag(gid - NF0, 96, Wl1, Wr1, wp1);
        else if (gid < NF0 + NF1 + NF2) pack_frag(gid - NF0 - NF1, 64, Wl2, Wr2, wp2);
        if (gid < NG) {
            int g = gid;
            int lo = 0, hi = NN;
            while (lo < hi) { int m = (lo + hi) >> 1; if (batch[m] < g) lo = m + 1; else hi = m; }
            int start = lo;
            hi = NN;
            while (lo < hi) { int m = (lo + hi) >> 1; if (batch[m] < g + 1) lo = m + 1; else hi = m; }
            inv_cnt[g] = 1.f / (float)max(lo - start, 1);
        }
    }
}

// ---------------- csr_build body (per-bucket CSR, u16 indices + packed offs|deg) -------
static __device__ void csr_build_body(int b, char* smem, const uint_t* __restrict__ part,
                                      const int* __restrict__ bucket_cnt,
                                      uint_t* __restrict__ od, ushort_t* __restrict__ csr) {
    uint_t* stage = (uint_t*)smem;                       // 16384 B
    ushort_t* cstage = (ushort_t*)(smem + 16384);        // 8192 B
    int* cnt_s = (int*)(smem + 24576);                   // 1024 B
    int* scan_l = (int*)(smem + 25600);                  // 1024 B
    int* cur_l = (int*)(smem + 26624);                   // 1024 B
    int tid = threadIdx.x;
    int bc = bucket_cnt[tid];
    cnt_s[tid] = bc;
    scan_l[tid] = bc;
    __syncthreads();
    for (int off = 1; off < NBKT; off <<= 1) {
        int t = (tid >= off) ? scan_l[tid - off] : 0;
        __syncthreads();
        scan_l[tid] += t;
        __syncthreads();
    }
    int base = scan_l[b] - cnt_s[b];
    int n = cnt_s[b];
    __syncthreads();
    cnt_s[tid] = 0;                           // reuse as deg_l
    __syncthreads();
    for (int i = tid; i < n; i += 256) {
        uint_t e = part[(size_t)b * BCAP + i];
        stage[i] = e;
        atomicAdd(&cnt_s[e >> 16], 1);
    }
    __syncthreads();
    int v = cnt_s[tid];
    scan_l[tid] = v;
    __syncthreads();
    for (int off = 1; off < NBKT; off <<= 1) {
        int t = (tid >= off) ? scan_l[tid - off] : 0;
        __syncthreads();
        scan_l[tid] += t;
        __syncthreads();
    }
    int ex = scan_l[tid] - v;
    scan_l[tid] = ex;
    cur_l[tid] = 0;
    __syncthreads();
    int g = b * NPB + tid;
    // packed descriptor: offs in bits [31:8], deg in bits [7:0]
    if (tid < NPB && g < NN) od[g] = ((uint_t)(base + ex) << 8) | (uint_t)v;
    for (int i = tid; i < n; i += 256) {
        uint_t e = stage[i];
        int dl = e >> 16;
        int p = atomicAdd(&cur_l[dl], 1);
        cstage[scan_l[dl] + p] = (ushort_t)(e & 0xFFFFu);
    }
    __syncthreads();
    for (int i = tid; i < n; i += 256) csr[base + i] = cstage[i];
}

// ---------------- K2: csr_build (blocks 0..255) + transform layer0 (rest) ----------------
// Layer-0 transform reads x (fp32) + global wpack0 B-frags (no LDS weight staging).
__launch_bounds__(256) static __global__
void csr_tf0_kernel(const uint_t* __restrict__ part, const int* __restrict__ bucket_cnt,
                    uint_t* __restrict__ od, ushort_t* __restrict__ csr,
                    const float* __restrict__ x, const ushort_t* __restrict__ wp0,
                    const float* __restrict__ b0,
                    ushort_t* __restrict__ tlc, ushort_t* __restrict__ trc) {
    __shared__ __align__(16) char smem[27648];
    if (blockIdx.x < NBKT) {
        csr_build_body(blockIdx.x, smem, part, bucket_cnt, od, csr);
        return;
    }
    int bid = blockIdx.x - NBKT;
    int tid = threadIdx.x;
    int lane = tid & 63;
    int m0 = bid * 64 + (tid >> 6) * 16;
    int row = m0 + (lane & 15);
    const float* xr = x + (size_t)min(row, NN - 1) * 96 + (lane >> 4) * 8;
    bf16x8 a0, a1, a2;
#pragma unroll
    for (int s = 0; s < 3; s++) {
        float4 v0 = *(const float4*)(xr + s * 32);
        float4 v1 = *(const float4*)(xr + s * 32 + 4);
        bf16x8 pk;
        pk[0] = (short)f2b(v0.x); pk[1] = (short)f2b(v0.y);
        pk[2] = (short)f2b(v0.z); pk[3] = (short)f2b(v0.w);
        pk[4] = (short)f2b(v1.x); pk[5] = (short)f2b(v1.y);
        pk[6] = (short)f2b(v1.z); pk[7] = (short)f2b(v1.w);
        if (s == 0) a0 = pk; else if (s == 1) a1 = pk; else a2 = pk;
    }
    const bf16x8* wp = (const bf16x8*)wp0 + lane;
    int quad = lane >> 4, col = lane & 15;
#pragma unroll
    for (int t = 0; t < 12; t++) {
        f32x4 acc = (f32x4){0.f, 0.f, 0.f, 0.f};
        acc = __builtin_amdgcn_mfma_f32_16x16x32_bf16(a0, wp[(t * 3 + 0) * 64], acc, 0, 0, 0);
        acc = __builtin_amdgcn_mfma_f32_16x16x32_bf16(a1, wp[(t * 3 + 1) * 64], acc, 0, 0, 0);
        acc = __builtin_amdgcn_mfma_f32_16x16x32_bf16(a2, wp[(t * 3 + 2) * 64], acc, 0, 0, 0);
        int o = t * 16 + col;
        bool is_r = (o >= 96);
        float bv = is_r ? b0[o - 96] : 0.f;
        ushort_t* outp = is_r ? trc : tlc;
        int oo = is_r ? (o - 96) : o;
        int cch = oo >> 5, f = oo & 31;
        ushort_t* ob = outp + ((size_t)cch * NN) * 32 + f;
#pragma unroll
        for (int r = 0; r < 4; r++) {
            int node = m0 + quad * 4 + r;
            if (node < NN) ob[(size_t)node * 32] = f2b(acc[r] + bv);
        }
    }
}

// ---------------- gather inner loop (R3-verified tier cascade) ----------------
static __device__ inline void gather_accum(const uint_t* __restrict__ tl,
                                           const ushort_t* __restrict__ csr,
                                           int off, int dg, int ng, int fl,
                                           float* __restrict__ acc) {
    int k = 0;
    for (; k + 16 <= dg; k += 16) {
        int s0 = csr[off + k + ng];
        int s1 = csr[off + k + 4 + ng];
        int s2 = csr[off + k + 8 + ng];
        int s3 = csr[off + k + 12 + ng];
        uint4 a0 = *(const uint4*)(tl + (size_t)s0 * 16 + 4 * fl);
        uint4 a1 = *(const uint4*)(tl + (size_t)s1 * 16 + 4 * fl);
        uint4 a2 = *(const uint4*)(tl + (size_t)s2 * 16 + 4 * fl);
        uint4 a3 = *(const uint4*)(tl + (size_t)s3 * 16 + 4 * fl);
        acc[0] += (blo(a0.x) + blo(a1.x)) + (blo(a2.x) + blo(a3.x));
        acc[1] += (bhi(a0.x) + bhi(a1.x)) + (bhi(a2.x) + bhi(a3.x));
        acc[2] += (blo(a0.y) + blo(a1.y)) + (blo(a2.y) + blo(a3.y));
        acc[3] += (bhi(a0.y) + bhi(a1.y)) + (bhi(a2.y) + bhi(a3.y));
        acc[4] += (blo(a0.z) + blo(a1.z)) + (blo(a2.z) + blo(a3.z));
        acc[5] += (bhi(a0.z) + bhi(a1.z)) + (bhi(a2.z) + bhi(a3.z));
        acc[6] += (blo(a0.w) + blo(a1.w)) + (blo(a2.w) + blo(a3.w));
        acc[7] += (bhi(a0.w) + bhi(a1.w)) + (bhi(a2.w) + bhi(a3.w));
    }
    if (k + 8 <= dg) {
        int s0 = csr[off + k + ng];
        int s1 = csr[off + k + 4 + ng];
        uint4 a0 = *(const uint4*)(tl + (size_t)s0 * 16 + 4 * fl);
        uint4 a1 = *(const uint4*)(tl + (size_t)s1 * 16 + 4 * fl);
        acc[0] += blo(a0.x) + blo(a1.x); acc[1] += bhi(a0.x) + bhi(a1.x);
        acc[2] += blo(a0.y) + blo(a1.y); acc[3] += bhi(a0.y) + bhi(a1.y);
        acc[4] += blo(a0.z) + blo(a1.z); acc[5] += bhi(a0.z) + bhi(a1.z);
        acc[6] += blo(a0.w) + blo(a1.w); acc[7] += bhi(a0.w) + bhi(a1.w);
        k += 8;
    }
    if (k + 4 <= dg) {
        int s0 = csr[off + k + ng];
        uint4 a0 = *(const uint4*)(tl + (size_t)s0 * 16 + 4 * fl);
        acc[0] += blo(a0.x); acc[1] += bhi(a0.x);
        acc[2] += blo(a0.y); acc[3] += bhi(a0.y);
        acc[4] += blo(a0.z); acc[5] += bhi(a0.z);
        acc[6] += blo(a0.w); acc[7] += bhi(a0.w);
        k += 4;
    }
    if (ng < dg - k) {
        int s0 = csr[off + k + ng];
        uint4 a0 = *(const uint4*)(tl + (size_t)s0 * 16 + 4 * fl);
        acc[0] += blo(a0.x); acc[1] += bhi(a0.x);
        acc[2] += blo(a0.y); acc[3] += bhi(a0.y);
        acc[4] += blo(a0.z); acc[5] += bhi(a0.z);
        acc[6] += blo(a0.w); acc[7] += bhi(a0.w);
    }
}

// ---------------- fused agg + transform (R9: occupancy-fixed) ----------------
// 32 nodes/block, 1563 blocks (~6/CU vs R8's 3/CU), LDS = 6144B h-tile only
// (weights pre-packed in global wpack, L2-hot). 6 serial gather units/block (was 12).
template <int DOUT, int NT>
__launch_bounds__(256) static __global__
void aggtf_kernel(const ushort_t* __restrict__ tlin, const ushort_t* __restrict__ trin,
                  const uint_t* __restrict__ od, const ushort_t* __restrict__ csr,
                  const ushort_t* __restrict__ wpack, const float* __restrict__ bias,
                  ushort_t* __restrict__ tlo, ushort_t* __restrict__ tro) {
    __shared__ __align__(16) uint_t hbuf[32 * 48];       // [32 nodes][96 bf16] = 6144 B
    int tid = threadIdx.x;
    int bid = blockIdx.x;
    int l16 = tid & 15;
    int ng = l16 >> 2, fl = l16 & 3;
    // ---- phase 1: gather-agg 32 nodes, chunk-major (2 groups of 16 per chunk)
    for (int c = 0; c < 3; c++) {
        const uint_t* tl = (const uint_t*)tlin + (size_t)c * NN * 16;
        const uint_t* trb = (const uint_t*)trin + (size_t)c * NN * 16;
#pragma unroll
        for (int g = 0; g < 2; g++) {
            int nloc = g * 16 + (tid >> 4);
            int node = bid * 32 + nloc;
            uint_t pd = od[min(node, NN - 1)];
            int off = (int)(pd >> 8);
            int dg = (node < NN) ? (int)(pd & 255u) : 0;
            float acc[8];
#pragma unroll
            for (int q = 0; q < 8; q++) acc[q] = 0.f;
            gather_accum(tl, csr, off, dg, ng, fl, acc);
#pragma unroll
            for (int q = 0; q < 8; q++) {
                acc[q] += __shfl_xor(acc[q], 4, 64);
                acc[q] += __shfl_xor(acc[q], 8, 64);
            }
            float s = 1.f / (float)max(dg, 1);
            u32x4 t = __builtin_nontemporal_load(
                (const u32x4*)(trb + (size_t)min(node, NN - 1) * 16 + 4 * fl));
            if (ng == 0) {
                float v0 = fmaxf(fmaf(acc[0], s, blo(t.x)), 0.f);
                float v1 = fmaxf(fmaf(acc[1], s, bhi(t.x)), 0.f);
                float v2 = fmaxf(fmaf(acc[2], s, blo(t.y)), 0.f);
                float v3 = fmaxf(fmaf(acc[3], s, bhi(t.y)), 0.f);
                float v4 = fmaxf(fmaf(acc[4], s, blo(t.z)), 0.f);
                float v5 = fmaxf(fmaf(acc[5], s, bhi(t.z)), 0.f);
                float v6 = fmaxf(fmaf(acc[6], s, blo(t.w)), 0.f);
                float v7 = fmaxf(fmaf(acc[7], s, bhi(t.w)), 0.f);
                u32x4 o;
                o.x = (uint_t)f2b(v0) | ((uint_t)f2b(v1) << 16);
                o.y = (uint_t)f2b(v2) | ((uint_t)f2b(v3) << 16);
                o.z = (uint_t)f2b(v4) | ((uint_t)f2b(v5) << 16);
                o.w = (uint_t)f2b(v6) | ((uint_t)f2b(v7) << 16);
                *(u32x4*)&hbuf[nloc * 48 + c * 16 + 4 * fl] = o;
            }
        }
    }
    __syncthreads();
    // ---- phase 2: MFMA. wave w: row-tile (w&1), col-half (w>>1). B-frags from global.
    int lane = tid & 63, w = tid >> 6;
    int rt = w & 1, cb = (w >> 1) * (NT / 2);
    int row = rt * 16 + (lane & 15);
    const ushort_t* hb = (const ushort_t*)hbuf;
    const ushort_t* hr = hb + row * 96 + (lane >> 4) * 8;
    bf16x8 a0 = *(const bf16x8*)(hr);
    bf16x8 a1 = *(const bf16x8*)(hr + 32);
    bf16x8 a2 = *(const bf16x8*)(hr + 64);
    const bf16x8* wp = (const bf16x8*)wpack + lane;
    int quad = lane >> 4, col = lane & 15;
    int m0 = bid * 32 + rt * 16;
#pragma unroll
    for (int t = 0; t < NT / 2; t++) {
        int tt = cb + t;
        f32x4 acc = (f32x4){0.f, 0.f, 0.f, 0.f};
        acc = __builtin_amdgcn_mfma_f32_16x16x32_bf16(a0, wp[(tt * 3 + 0) * 64], acc, 0, 0, 0);
        acc = __builtin_amdgcn_mfma_f32_16x16x32_bf16(a1, wp[(tt * 3 + 1) * 64], acc, 0, 0, 0);
        acc = __builtin_amdgcn_mfma_f32_16x16x32_bf16(a2, wp[(tt * 3 + 2) * 64], acc, 0, 0, 0);
        int o = tt * 16 + col;
        bool is_r = (o >= DOUT);
        float bv = is_r ? bias[o - DOUT] : 0.f;
        ushort_t* outp = is_r ? tro : tlo;
        int oo = is_r ? (o - DOUT) : o;
        int cch = oo >> 5, f = oo & 31;
        ushort_t* ob = outp + ((size_t)cch * NN) * 32 + f;
#pragma unroll
        for (int r = 0; r < 4; r++) {
            int node = m0 + quad * 4 + r;
            if (node < NN) ob[(size_t)node * 32] = f2b(acc[r] + bv);
        }
    }
}

// ---------------- final agg + pool fused (D=64, no relu), pre-divided atomics -------
__launch_bounds__(256) static __global__
void agg_pool_kernel(const ushort_t* __restrict__ tlc, const ushort_t* __restrict__ trc,
                     const uint_t* __restrict__ od, const ushort_t* __restrict__ csr,
                     const int* __restrict__ batch,
                     const float* __restrict__ inv_cnt, float* __restrict__ out) {
    __shared__ float hsum[16][32];
    __shared__ int gids[16];
    int bx = blockIdx.x;
    int c = bx / AGB;
    int b = bx - c * AGB;
    int tid = threadIdx.x;
    int nl = tid >> 4;
    int node = b * 16 + nl;
    int lane = tid & 15;
    int ng = lane >> 2, fl = lane & 3;
    if (tid < 16) gids[tid] = batch[b * 16 + tid];
    const uint_t* tl = (const uint_t*)tlc + (size_t)c * NN * 16;
    uint_t pd = od[node];
    int off = (int)(pd >> 8), dg = (int)(pd & 255u);
    float acc[8];
#pragma unroll
    for (int q = 0; q < 8; q++) acc[q] = 0.f;
    gather_accum(tl, csr, off, dg, ng, fl, acc);
#pragma unroll
    for (int q = 0; q < 8; q++) {
        acc[q] += __shfl_xor(acc[q], 4, 64);
        acc[q] += __shfl_xor(acc[q], 8, 64);
    }
    float s = 1.f / (float)max(dg, 1);
    u32x4 t = __builtin_nontemporal_load(
        (const u32x4*)((const uint_t*)trc + (size_t)c * NN * 16 + (size_t)node * 16 + 4 * fl));
    if (ng == 0) {
        hsum[nl][8 * fl + 0] = fmaf(acc[0], s, blo(t.x));
        hsum[nl][8 * fl + 1] = fmaf(acc[1], s, bhi(t.x));
        hsum[nl][8 * fl + 2] = fmaf(acc[2], s, blo(t.y));
        hsum[nl][8 * fl + 3] = fmaf(acc[3], s, bhi(t.y));
        hsum[nl][8 * fl + 4] = fmaf(acc[4], s, blo(t.z));
        hsum[nl][8 * fl + 5] = fmaf(acc[5], s, bhi(t.z));
        hsum[nl][8 * fl + 6] = fmaf(acc[6], s, blo(t.w));
        hsum[nl][8 * fl + 7] = fmaf(acc[7], s, bhi(t.w));
    }
    __syncthreads();
    if (tid < 32) {
        int gcur = gids[0];
        float ps = 0.f;
        for (int j = 0; j < 16; j++) {
            int g = gids[j];
            if (g != gcur) {
                atomicAdd(&out[gcur * 64 + c * 32 + tid], ps * inv_cnt[gcur]);
                ps = 0.f; gcur = g;
            }
            ps += hsum[j][tid];
        }
        atomicAdd(&out[gcur * 64 + c * 32 + tid], ps * inv_cnt[gcur]);
    }
}

// ---------------- launch: 5 dispatches ----------------
extern "C" void kernel_launch(void* const* d_in, const int* in_sizes, int n_in,
                              void* d_out, int out_size, void* d_ws, size_t ws_size,
                              hipStream_t stream) {
    (void)in_sizes; (void)n_in; (void)out_size; (void)ws_size;
    const float* x   = (const float*)d_in[0];
    const int*   ei  = (const int*)d_in[1];
    const int*   bat = (const int*)d_in[2];
    const float* Wl0 = (const float*)d_in[3];
    const float* b0  = (const float*)d_in[4];
    const float* Wr0 = (const float*)d_in[5];
    const float* Wl1 = (const float*)d_in[6];
    const float* b1  = (const float*)d_in[7];
    const float* Wr1 = (const float*)d_in[8];
    const float* Wl2 = (const float*)d_in[9];
    const float* b2  = (const float*)d_in[10];
    const float* Wr2 = (const float*)d_in[11];
    float* out = (float*)d_out;
    const int* src = ei;
    const int* dst = ei + NE;

    char* p = (char*)d_ws;
    auto carve = [&](size_t bytes) -> char* {
        char* r = p;
        p += (bytes + 255) & ~(size_t)255;
        return r;
    };
    uint_t*   od     = (uint_t*)carve((size_t)NN * 4);          // packed offs<<8 | deg
    int*      bucket_cnt = (int*)carve(NBKT * 4);
    float*    inv_cnt = (float*)carve(NG * 4);
    uint_t*   part   = (uint_t*)carve((size_t)NBKT * BCAP * 4);
    ushort_t* csr    = (ushort_t*)carve((size_t)NE * 2);        // u16 src indices
    ushort_t* wp0    = (ushort_t*)carve((size_t)NF0 * 16);      // packed bf16 B-frags
    ushort_t* wp1    = (ushort_t*)carve((size_t)NF1 * 16);
    ushort_t* wp2    = (ushort_t*)carve((size_t)NF2 * 16);
    ushort_t* tlcA   = (ushort_t*)carve((size_t)3 * NN * 32 * 2);  // chunk-major ping
    ushort_t* trcA   = (ushort_t*)carve((size_t)3 * NN * 32 * 2);
    ushort_t* tlcB   = (ushort_t*)carve((size_t)3 * NN * 32 * 2);  // chunk-major pong
    ushort_t* trcB   = (ushort_t*)carve((size_t)3 * NN * 32 * 2);

    dim3 b256(256);
    hipMemsetAsync(bucket_cnt, 0, NBKT * 4, stream);

    part_zero_kernel<<<dim3(PARTB + 32), b256, 0, stream>>>(src, dst, bucket_cnt, part,
                                                            out, bat, inv_cnt,
                                                            Wl0, Wr0, Wl1, Wr1, Wl2, Wr2,
                                                            wp0, wp1, wp2);
    csr_tf0_kernel<<<dim3(NBKT + TFB), b256, 0, stream>>>(part, bucket_cnt, od, csr,
                                                          x, wp0, b0, tlcA, trcA);
    aggtf_kernel<96, 12><<<dim3(AGB32), b256, 0, stream>>>(tlcA, trcA, od, csr,
                                                           wp1, b1, tlcB, trcB);
    aggtf_kernel<64, 8><<<dim3(AGB32), b256, 0, stream>>>(tlcB, trcB, od, csr,
                                                          wp2, b2, tlcA, trcA);
    agg_pool_kernel<<<dim3(2 * AGB), b256, 0, stream>>>(tlcA, trcA, od, csr, bat,
                                                        inv_cnt, out);
}